// Round 4
// baseline (47.398 us; speedup 1.0000x reference)
//
#include <hip/hip_runtime.h>

#define OC 64
#define IC 32
#define KC 16

typedef __attribute__((ext_vector_type(8))) short bf16x8;
typedef __attribute__((ext_vector_type(4))) float f32x4;

__device__ inline unsigned short f2bf(float f) {
    unsigned u = __builtin_bit_cast(unsigned, f);
    unsigned r = (u + 0x7fffu + ((u >> 16) & 1u)) >> 16;
    return (unsigned short)r;
}

// ---------------------------------------------------------------------------
// Kernel 1: build trilinear kernel -> bf16 Kb[cell=125][o=64][c=32]
// ---------------------------------------------------------------------------
__global__ __launch_bounds__(128) void build_k(const float* __restrict__ W,
                                               const float* __restrict__ P,
                                               short* __restrict__ Kb) {
    const int pair = blockIdx.x;      // 0..2047
    const int o = pair >> 5;
    const int c = pair & 31;
    const int cell = threadIdx.x;
    if (cell >= 125) return;
    const int l = cell / 25;
    const int j = (cell / 5) % 5;
    const int i = cell % 5;
    const float fl = (float)l, fj = (float)j, fi = (float)i;
    const int base = (o * IC + c) * KC;
    float acc = 0.f;
    #pragma unroll
    for (int k = 0; k < KC; ++k) {
        const float w  = W[base + k];
        const float p1 = P[0 * OC * IC * KC + base + k] + 2.0f;  // depth
        const float p2 = P[1 * OC * IC * KC + base + k] + 2.0f;  // width
        const float p3 = P[2 * OC * IC * KC + base + k] + 2.0f;  // height
        const float f1 = floorf(p1), r1 = p1 - f1;
        const float f2 = floorf(p2), r2 = p2 - f2;
        const float f3 = floorf(p3), r3 = p3 - f3;
        const float wl = (fl == f1) ? (1.f - r1) : ((fl == f1 + 1.f) ? r1 : 0.f);
        const float wj = (fj == f3) ? (1.f - r3) : ((fj == f3 + 1.f) ? r3 : 0.f);
        const float wi = (fi == f2) ? (1.f - r2) : ((fi == f2 + 1.f) ? r2 : 0.f);
        acc += w * (wl * wj * wi);
    }
    Kb[(cell * OC + o) * IC + c] = (short)f2bf(acc);
}

// ---------------------------------------------------------------------------
// Kernel 2: transpose + zero-pad x -> bf16 x_p[n][z=20][h=36][w=36][slot=4][8c]
// slot s at width w holds channel-group (s ^ (w&3))  (source-side XOR swizzle)
// ---------------------------------------------------------------------------
__global__ __launch_bounds__(128) void xpose(const float* __restrict__ x,
                                             short* __restrict__ xp) {
    const int b = blockIdx.x;          // 0..1439 = n(2) x z(20) x h(36)
    const int n = b / 720;
    const int rem = b - n * 720;
    const int z = rem / 36;
    const int h = rem - z * 36;
    const int zr = z - 2, hr = h - 2;
    short* orow = xp + (size_t)((n * 20 + z) * 36 + h) * (36 * 32);

    if ((unsigned)zr >= 16u || (unsigned)hr >= 32u) {
        for (int idx = threadIdx.x; idx < 144; idx += 128)
            *reinterpret_cast<float4*>(orow + idx * 8) = make_float4(0.f, 0.f, 0.f, 0.f);
        return;
    }

    __shared__ float sR[32][36];
    const float* xb = x + ((size_t)(n * 32) * 16 + zr) * 1024 + hr * 32;
    for (int idx = threadIdx.x; idx < 32 * 36; idx += 128) {
        const int c = idx / 36;
        const int w = idx - c * 36;
        const int wr = w - 2;
        float v = 0.f;
        if ((unsigned)wr < 32u) v = xb[(size_t)c * 16384 + wr];
        sR[c][w] = v;
    }
    __syncthreads();
    for (int idx = threadIdx.x; idx < 144; idx += 128) {
        const int w = idx >> 2;
        const int s = idx & 3;
        const int c0 = (s ^ (w & 3)) * 8;
        bf16x8 pk;
        #pragma unroll
        for (int e = 0; e < 8; ++e) pk[e] = (short)f2bf(sR[c0 + e][w]);
        *reinterpret_cast<bf16x8*>(orow + idx * 8) = pk;
    }
}

// ---------------------------------------------------------------------------
// Kernel 3: implicit-GEMM conv, o-split + rolling z-plane double buffer.
// Grid 512 = [n2][d16][hb8][og2]; block 256 thr = 4 waves (wave = 1 h-row).
// Wave tile: 2 o-frags (og*32 + {0,16}) x 2 w-frags ({0,16}).
// LDS: 2 x 18432B plane buffers -> 2 blocks/CU.
// Per (l): stage plane l+1 async, 25 taps pipelined (A dist-1 global,
// B dist-1 LDS), one barrier per plane.
// ---------------------------------------------------------------------------
__global__ __launch_bounds__(256, 2) void conv_mfma(const short* __restrict__ Kb,
                                                    const short* __restrict__ xp,
                                                    const float* __restrict__ bias,
                                                    float* __restrict__ out) {
    // XCD-aware chunked swizzle (512 % 8 == 0 -> bijective)
    const int bx = (blockIdx.x & 7) * 64 + (blockIdx.x >> 3);
    const int og = bx & 1;
    const int hb = (bx >> 1) & 7;
    const int d  = (bx >> 4) & 15;
    const int n  = bx >> 8;
    const int h0 = hb * 4;

    __shared__ short sX[2][8 * 36 * 32];   // 2 x 18432 B

    const int tid  = threadIdx.x;
    const int rr   = tid >> 6;             // wave id = h-row within block
    const int lane = tid & 63;
    const int col  = lane & 15;
    const int cg   = lane >> 4;

    const short* srcbase = xp + (size_t)((n * 20 + d) * 36 + h0) * 1152;

#define STAGE(L, B)                                                           \
    {                                                                         \
        const short* s_ = srcbase + (L) * 41472;                              \
        _Pragma("unroll")                                                     \
        for (int k_ = 0; k_ < 4; ++k_) {                                      \
            const int t_ = k_ * 256 + tid;                                    \
            __builtin_amdgcn_global_load_lds(                                 \
                (const __attribute__((address_space(1))) unsigned int*)(s_ + t_ * 8), \
                (__attribute__((address_space(3))) unsigned int*)(&sX[B][0] + t_ * 8), \
                16, 0, 0);                                                    \
        }                                                                     \
        if (tid < 128) {                                                      \
            const int t_ = 1024 + tid;                                        \
            __builtin_amdgcn_global_load_lds(                                 \
                (const __attribute__((address_space(1))) unsigned int*)(s_ + t_ * 8), \
                (__attribute__((address_space(3))) unsigned int*)(&sX[B][0] + t_ * 8), \
                16, 0, 0);                                                    \
        }                                                                     \
    }

    // A base: Kb[cell][og*32 + mf*16 + col][cg*8..], cell stride 2048 shorts
    const short* Abase = Kb + (og * 32 + col) * 32 + cg * 8;

    // per-lane swizzled B offsets (shorts) within a zh-row of a plane
    int boff[2][5];
    #pragma unroll
    for (int f = 0; f < 2; ++f)
        #pragma unroll
        for (int i = 0; i < 5; ++i) {
            const int w = col + f * 16 + i;
            boff[f][i] = w * 32 + ((cg ^ (w & 3)) << 3);
        }

    f32x4 acc[2][2] = {{{0.f, 0.f, 0.f, 0.f}, {0.f, 0.f, 0.f, 0.f}},
                       {{0.f, 0.f, 0.f, 0.f}, {0.f, 0.f, 0.f, 0.f}}};

    bf16x8 Ab[2][2][5];   // [parity][mf][i]
    bf16x8 Bb[2][2][5];   // [parity][f][i]

#define LOADA(P, ROW)                                                         \
    {                                                                         \
        const short* pa_ = Abase + (ROW) * 10240;                             \
        _Pragma("unroll")                                                     \
        for (int i_ = 0; i_ < 5; ++i_) {                                      \
            Ab[P][0][i_] = *reinterpret_cast<const bf16x8*>(pa_ + i_ * 2048); \
            Ab[P][1][i_] = *reinterpret_cast<const bf16x8*>(pa_ + i_ * 2048 + 512); \
        }                                                                     \
    }

#define LOADB(P, BUF, J)                                                      \
    {                                                                         \
        const short* pb_ = &sX[BUF][0] + (rr + (J)) * 1152;                   \
        _Pragma("unroll")                                                     \
        for (int i_ = 0; i_ < 5; ++i_) {                                      \
            Bb[P][0][i_] = *reinterpret_cast<const bf16x8*>(pb_ + boff[0][i_]); \
            Bb[P][1][i_] = *reinterpret_cast<const bf16x8*>(pb_ + boff[1][i_]); \
        }                                                                     \
    }

#define MFMA_ROW(P)                                                           \
    {                                                                         \
        __builtin_amdgcn_s_setprio(1);                                        \
        _Pragma("unroll")                                                     \
        for (int i_ = 0; i_ < 5; ++i_) {                                      \
            acc[0][0] = __builtin_amdgcn_mfma_f32_16x16x32_bf16(Ab[P][0][i_], Bb[P][0][i_], acc[0][0], 0, 0, 0); \
            acc[0][1] = __builtin_amdgcn_mfma_f32_16x16x32_bf16(Ab[P][0][i_], Bb[P][1][i_], acc[0][1], 0, 0, 0); \
            acc[1][0] = __builtin_amdgcn_mfma_f32_16x16x32_bf16(Ab[P][1][i_], Bb[P][0][i_], acc[1][0], 0, 0, 0); \
            acc[1][1] = __builtin_amdgcn_mfma_f32_16x16x32_bf16(Ab[P][1][i_], Bb[P][1][i_], acc[1][1], 0, 0, 0); \
        }                                                                     \
        __builtin_amdgcn_s_setprio(0);                                        \
    }

    // ---- prologue: A row 0 + plane 0 ----
    LOADA(0, 0);
    STAGE(0, 0);
    __syncthreads();                 // drains vmcnt (plane0 + A row0)
    LOADB(0, 0, 0);

    #pragma unroll
    for (int l = 0; l < 5; ++l) {
        const int cur = l & 1;
        if (l < 4) STAGE(l + 1, cur ^ 1);
        #pragma unroll
        for (int j = 0; j < 5; ++j) {
            const int r = l * 5 + j;
            const int p = r & 1;
            if (r + 1 < 25) LOADA(p ^ 1, r + 1);
            if (j < 4)      LOADB(p ^ 1, cur, j + 1);
            MFMA_ROW(p);
        }
        if (l < 4) {
            __syncthreads();         // compiler drains vmcnt+lgkm before barrier
            LOADB(((l + 1) * 5) & 1, cur ^ 1, 0);
        }
    }

#undef STAGE
#undef LOADA
#undef LOADB
#undef MFMA_ROW

    // ---- epilogue: D layout col=lane&15 (w), row=cg*4+reg (o) ----
    const int h = h0 + rr;
    #pragma unroll
    for (int mf = 0; mf < 2; ++mf) {
        #pragma unroll
        for (int f = 0; f < 2; ++f) {
            #pragma unroll
            for (int reg = 0; reg < 4; ++reg) {
                const int o = og * 32 + mf * 16 + cg * 4 + reg;
                const int w = f * 16 + col;
                out[(((size_t)(n * 64 + o) * 16 + d) * 32 + h) * 32 + w] =
                    acc[mf][f][reg] + bias[o];
            }
        }
    }
}

extern "C" void kernel_launch(void* const* d_in, const int* in_sizes, int n_in,
                              void* d_out, int out_size, void* d_ws, size_t ws_size,
                              hipStream_t stream) {
    const float* x    = (const float*)d_in[0];
    const float* W    = (const float*)d_in[1];
    const float* P    = (const float*)d_in[2];
    const float* bias = (const float*)d_in[3];
    float* outp = (float*)d_out;

    short* Kb = (short*)d_ws;                          // 125*64*32*2 = 512000 B
    short* xp = (short*)((char*)d_ws + 524288);        // 2*20*36*36*64 = 3317760 B

    build_k<<<OC * IC, 128, 0, stream>>>(W, P, Kb);
    xpose<<<2 * 20 * 36, 128, 0, stream>>>(x, xp);
    conv_mfma<<<512, 256, 0, stream>>>(Kb, xp, bias, outp);
}

// Round 5
// 38.570 us; speedup vs baseline: 1.2289x; 1.2289x over previous
//
#include <hip/hip_runtime.h>

#define OC 64
#define IC 32
#define KC 16

typedef __attribute__((ext_vector_type(8))) short bf16x8;
typedef __attribute__((ext_vector_type(16))) float f32x16;

__device__ inline unsigned short f2bf(float f) {
    unsigned u = __builtin_bit_cast(unsigned, f);
    unsigned r = (u + 0x7fffu + ((u >> 16) & 1u)) >> 16;
    return (unsigned short)r;
}

// ---------------------------------------------------------------------------
// Fused prep: blocks [0,1440): xpose; blocks [1440, 3488): build_k.
// xpose: x (NCDHW f32) -> bf16 xp[n][z=20][h=36][cg=4][w=36][c=8]
//        (zero-padded z/h/w by 2; NO swizzle — layout is conflict-free for
//         the conv's ds_read pattern by construction)
// build_k: trilinear kernel -> bf16 Kb[cell=125][o=64][c=32]
// ---------------------------------------------------------------------------
__global__ __launch_bounds__(128) void prep(const float* __restrict__ x,
                                            const float* __restrict__ W,
                                            const float* __restrict__ P,
                                            short* __restrict__ xp,
                                            short* __restrict__ Kb) {
    const int b = blockIdx.x;
    if (b < 1440) {
        // ---------------- xpose ----------------
        const int n = b / 720;
        const int rem = b - n * 720;
        const int z = rem / 36;
        const int h = rem - z * 36;
        const int zr = z - 2, hr = h - 2;
        short* orow = xp + (size_t)((n * 20 + z) * 36 + h) * 1152;

        if ((unsigned)zr >= 16u || (unsigned)hr >= 32u) {
            for (int idx = threadIdx.x; idx < 144; idx += 128)
                *reinterpret_cast<float4*>(orow + idx * 8) =
                    make_float4(0.f, 0.f, 0.f, 0.f);
            return;
        }

        __shared__ float sR[32][36];
        const float* xb = x + ((size_t)(n * 32) * 16 + zr) * 1024 + hr * 32;
        for (int idx = threadIdx.x; idx < 32 * 36; idx += 128) {
            const int c = idx / 36;
            const int w = idx - c * 36;
            const int wr = w - 2;
            float v = 0.f;
            if ((unsigned)wr < 32u) v = xb[(size_t)c * 16384 + wr];
            sR[c][w] = v;
        }
        __syncthreads();
        for (int idx = threadIdx.x; idx < 144; idx += 128) {
            const int cg = idx / 36;       // [cg][w] layout
            const int w  = idx - cg * 36;
            bf16x8 pk;
            #pragma unroll
            for (int e = 0; e < 8; ++e) pk[e] = (short)f2bf(sR[cg * 8 + e][w]);
            *reinterpret_cast<bf16x8*>(orow + idx * 8) = pk;
        }
    } else {
        // ---------------- build_k ----------------
        const int pair = b - 1440;        // 0..2047
        const int o = pair >> 5;
        const int c = pair & 31;
        const int cell = threadIdx.x;
        if (cell >= 125) return;
        const int l = cell / 25;
        const int j = (cell / 5) % 5;
        const int i = cell % 5;
        const float fl = (float)l, fj = (float)j, fi = (float)i;
        const int base = (o * IC + c) * KC;
        float acc = 0.f;
        #pragma unroll
        for (int k = 0; k < KC; ++k) {
            const float w  = W[base + k];
            const float p1 = P[0 * OC * IC * KC + base + k] + 2.0f;  // depth
            const float p2 = P[1 * OC * IC * KC + base + k] + 2.0f;  // width
            const float p3 = P[2 * OC * IC * KC + base + k] + 2.0f;  // height
            const float f1 = floorf(p1), r1 = p1 - f1;
            const float f2 = floorf(p2), r2 = p2 - f2;
            const float f3 = floorf(p3), r3 = p3 - f3;
            const float wl = (fl == f1) ? (1.f - r1) : ((fl == f1 + 1.f) ? r1 : 0.f);
            const float wj = (fj == f3) ? (1.f - r3) : ((fj == f3 + 1.f) ? r3 : 0.f);
            const float wi = (fi == f2) ? (1.f - r2) : ((fi == f2 + 1.f) ? r2 : 0.f);
            acc += w * (wl * wj * wi);
        }
        Kb[(cell * OC + o) * IC + c] = (short)f2bf(acc);
    }
}

// ---------------------------------------------------------------------------
// Conv: implicit GEMM via mfma_f32_32x32x16_bf16.
// Grid 256 = [n2][d16][hb4][og2], 1 block/CU. Block 256 thr = 4 waves,
// 1 wave/SIMD. Wave tile: 32 o x 2 adjacent h-rows x 32 w (2 accumulators).
// B-row carry: pt1's rows at step j == pt0's at step j+1 -> 10 new B frags
// per step instead of 20. A prefetch distance 2, B distance 1.
// LDS: 2 x 27648B plane buffers [12 rows][cg4][w36][c8] — ds_read_b128 is
// 256B-contiguous per quarter-wave (conflict-free, no swizzle).
// STAGE(l+1) issued late (j==3) so pre-barrier MFMA vmcnt waits never drain it.
// ---------------------------------------------------------------------------
__global__ __launch_bounds__(256, 1) void conv_mfma(const short* __restrict__ Kb,
                                                    const short* __restrict__ xp,
                                                    const float* __restrict__ bias,
                                                    float* __restrict__ out) {
    // XCD-aware chunked swizzle (256 % 8 == 0 -> bijective)
    const int sw = (blockIdx.x & 7) * 32 + (blockIdx.x >> 3);
    const int og = sw & 1;
    const int hb = (sw >> 1) & 3;
    const int d  = (sw >> 3) & 15;
    const int n  = sw >> 7;
    const int h0 = hb * 8;

    __shared__ short sB[2][13824];          // 2 x 27648 B

    const int tid  = threadIdx.x;
    const int wv   = tid >> 6;
    const int lane = tid & 63;
    const int wcol = lane & 31;
    const int hi   = lane >> 5;

    const short* Abase = Kb + (og * 32 + wcol) * 32 + hi * 8;
    const short* src0  = xp + ((size_t)(n * 20 + d) * 36 + h0) * 1152;
    const short* pbrow = &sB[0][0] + hi * 288 + wcol * 8;   // + buf*13824 + row*1152 + ch*576

    f32x16 acc0, acc1;
    for (int e = 0; e < 16; ++e) { acc0[e] = 0.f; acc1[e] = 0.f; }

    bf16x8 Ab[3][2][5];   // [slot][ch][i]
    bf16x8 Bb[3][2][5];   // [slot][ch][i]

#define STAGE(L, B)                                                           \
    {                                                                         \
        const short* s_ = src0 + (L) * 41472;                                 \
        _Pragma("unroll")                                                     \
        for (int k_ = 0; k_ < 6; ++k_) {                                      \
            const int t_ = k_ * 256 + tid;                                    \
            __builtin_amdgcn_global_load_lds(                                 \
                (const __attribute__((address_space(1))) unsigned int*)(s_ + t_ * 8), \
                (__attribute__((address_space(3))) unsigned int*)(&sB[B][0] + t_ * 8), \
                16, 0, 0);                                                    \
        }                                                                     \
        if (tid < 192) {                                                      \
            const int t_ = 1536 + tid;                                        \
            __builtin_amdgcn_global_load_lds(                                 \
                (const __attribute__((address_space(1))) unsigned int*)(s_ + t_ * 8), \
                (__attribute__((address_space(3))) unsigned int*)(&sB[B][0] + t_ * 8), \
                16, 0, 0);                                                    \
        }                                                                     \
    }

#define LOADA(S, ROW)                                                         \
    {                                                                         \
        const short* pa_ = Abase + (ROW) * 10240;                             \
        _Pragma("unroll")                                                     \
        for (int i_ = 0; i_ < 5; ++i_) {                                      \
            Ab[S][0][i_] = *reinterpret_cast<const bf16x8*>(pa_ + i_ * 2048); \
            Ab[S][1][i_] = *reinterpret_cast<const bf16x8*>(pa_ + i_ * 2048 + 16); \
        }                                                                     \
    }

#define LOADB(S, BUF, K)                                                      \
    {                                                                         \
        const short* pb_ = pbrow + (BUF) * 13824 + (2 * wv + (K)) * 1152;     \
        _Pragma("unroll")                                                     \
        for (int i_ = 0; i_ < 5; ++i_) {                                      \
            Bb[S][0][i_] = *reinterpret_cast<const bf16x8*>(pb_ + i_ * 8);    \
            Bb[S][1][i_] = *reinterpret_cast<const bf16x8*>(pb_ + 576 + i_ * 8); \
        }                                                                     \
    }

#define MFMA_STEP(RA, S0, S1)                                                 \
    {                                                                         \
        _Pragma("unroll")                                                     \
        for (int i_ = 0; i_ < 5; ++i_) {                                      \
            acc0 = __builtin_amdgcn_mfma_f32_32x32x16_bf16(Ab[RA][0][i_], Bb[S0][0][i_], acc0, 0, 0, 0); \
            acc1 = __builtin_amdgcn_mfma_f32_32x32x16_bf16(Ab[RA][0][i_], Bb[S1][0][i_], acc1, 0, 0, 0); \
            acc0 = __builtin_amdgcn_mfma_f32_32x32x16_bf16(Ab[RA][1][i_], Bb[S0][1][i_], acc0, 0, 0, 0); \
            acc1 = __builtin_amdgcn_mfma_f32_32x32x16_bf16(Ab[RA][1][i_], Bb[S1][1][i_], acc1, 0, 0, 0); \
        }                                                                     \
    }

    // ---- prologue ----
    LOADA(0, 0);
    LOADA(1, 1);
    STAGE(0, 0);
    __syncthreads();

    #pragma unroll
    for (int l = 0; l < 5; ++l) {
        const int buf = l & 1;
        LOADB(0, buf, 0);
        LOADB(1, buf, 1);
        #pragma unroll
        for (int j = 0; j < 5; ++j) {
            const int r = l * 5 + j;
            if (j == 3 && l < 4) STAGE(l + 1, buf ^ 1);
            if (r + 2 < 25) LOADA((r + 2) % 3, r + 2);
            if (j <= 3) LOADB((j + 2) % 3, buf, j + 2);
            MFMA_STEP(r % 3, j % 3, (j + 1) % 3);
        }
        if (l < 4) __syncthreads();
    }

#undef STAGE
#undef LOADA
#undef LOADB
#undef MFMA_STEP

    // ---- epilogue: D layout col=lane&31 (w), row=(reg&3)+8*(reg>>2)+4*hi (o) ----
    const int h = h0 + 2 * wv;
    #pragma unroll
    for (int reg = 0; reg < 16; ++reg) {
        const int o = og * 32 + (reg & 3) + 8 * (reg >> 2) + 4 * hi;
        const float bo = bias[o];
        float* op = out + (((size_t)(n * 64 + o) * 16 + d) * 32 + h) * 32 + wcol;
        op[0]  = acc0[reg] + bo;
        op[32] = acc1[reg] + bo;
    }
}

extern "C" void kernel_launch(void* const* d_in, const int* in_sizes, int n_in,
                              void* d_out, int out_size, void* d_ws, size_t ws_size,
                              hipStream_t stream) {
    const float* x    = (const float*)d_in[0];
    const float* W    = (const float*)d_in[1];
    const float* P    = (const float*)d_in[2];
    const float* bias = (const float*)d_in[3];
    float* outp = (float*)d_out;

    short* Kb = (short*)d_ws;                          // 125*64*32*2 = 512000 B
    short* xp = (short*)((char*)d_ws + 524288);        // 2*20*36*1152*2 = 3317760 B

    prep<<<1440 + 2048, 128, 0, stream>>>(x, W, P, xp, Kb);
    conv_mfma<<<256, 256, 0, stream>>>(Kb, xp, bias, outp);
}

// Round 6
// 28.643 us; speedup vs baseline: 1.6548x; 1.3466x over previous
//
#include <hip/hip_runtime.h>

#define OC 64
#define IC 32
#define KC 16

typedef __attribute__((ext_vector_type(8))) short bf16x8;
typedef __attribute__((ext_vector_type(16))) float f32x16;

__device__ inline unsigned short f2bf(float f) {
    unsigned u = __builtin_bit_cast(unsigned, f);
    unsigned r = (u + 0x7fffu + ((u >> 16) & 1u)) >> 16;
    return (unsigned short)r;
}

// ---------------------------------------------------------------------------
// Fused prep: blocks [0,1440): xpose; blocks [1440, 3488): build_k.
// xpose: x (NCDHW f32) -> bf16 xp[n][z=20][h=36][cg=4][w=36][c=8] (pad 2)
// build_k: trilinear kernel -> bf16 Kb[og=2][cell=125][kc=4][o=32][c8=8]
//          (per-(og,plane) slab of 25 cells is 51200 B CONTIGUOUS -> LDS-
//           stageable; ds_read of a frag is 512B-contiguous per half-wave)
// ---------------------------------------------------------------------------
__global__ __launch_bounds__(128) void prep(const float* __restrict__ x,
                                            const float* __restrict__ W,
                                            const float* __restrict__ P,
                                            short* __restrict__ xp,
                                            short* __restrict__ Kb) {
    const int b = blockIdx.x;
    if (b < 1440) {
        // ---------------- xpose ----------------
        const int n = b / 720;
        const int rem = b - n * 720;
        const int z = rem / 36;
        const int h = rem - z * 36;
        const int zr = z - 2, hr = h - 2;
        short* orow = xp + (size_t)((n * 20 + z) * 36 + h) * 1152;

        if ((unsigned)zr >= 16u || (unsigned)hr >= 32u) {
            for (int idx = threadIdx.x; idx < 144; idx += 128)
                *reinterpret_cast<float4*>(orow + idx * 8) =
                    make_float4(0.f, 0.f, 0.f, 0.f);
            return;
        }

        __shared__ float sR[32][36];
        const float* xb = x + ((size_t)(n * 32) * 16 + zr) * 1024 + hr * 32;
        for (int idx = threadIdx.x; idx < 32 * 36; idx += 128) {
            const int c = idx / 36;
            const int w = idx - c * 36;
            const int wr = w - 2;
            float v = 0.f;
            if ((unsigned)wr < 32u) v = xb[(size_t)c * 16384 + wr];
            sR[c][w] = v;
        }
        __syncthreads();
        for (int idx = threadIdx.x; idx < 144; idx += 128) {
            const int cg = idx / 36;       // [cg][w] layout
            const int w  = idx - cg * 36;
            bf16x8 pk;
            #pragma unroll
            for (int e = 0; e < 8; ++e) pk[e] = (short)f2bf(sR[cg * 8 + e][w]);
            *reinterpret_cast<bf16x8*>(orow + idx * 8) = pk;
        }
    } else {
        // ---------------- build_k ----------------
        const int pair = b - 1440;        // 0..2047
        const int o = pair >> 5;
        const int c = pair & 31;
        const int cell = threadIdx.x;
        if (cell >= 125) return;
        const int l = cell / 25;
        const int j = (cell / 5) % 5;
        const int i = cell % 5;
        const float fl = (float)l, fj = (float)j, fi = (float)i;
        const int base = (o * IC + c) * KC;
        float acc = 0.f;
        #pragma unroll
        for (int k = 0; k < KC; ++k) {
            const float w  = W[base + k];
            const float p1 = P[0 * OC * IC * KC + base + k] + 2.0f;  // depth
            const float p2 = P[1 * OC * IC * KC + base + k] + 2.0f;  // width
            const float p3 = P[2 * OC * IC * KC + base + k] + 2.0f;  // height
            const float f1 = floorf(p1), r1 = p1 - f1;
            const float f2 = floorf(p2), r2 = p2 - f2;
            const float f3 = floorf(p3), r3 = p3 - f3;
            const float wl = (fl == f1) ? (1.f - r1) : ((fl == f1 + 1.f) ? r1 : 0.f);
            const float wj = (fj == f3) ? (1.f - r3) : ((fj == f3 + 1.f) ? r3 : 0.f);
            const float wi = (fi == f2) ? (1.f - r2) : ((fi == f2 + 1.f) ? r2 : 0.f);
            acc += w * (wl * wj * wi);
        }
        // Kb[og][cell][kc][o&31][c&7]
        const int og = o >> 5;
        Kb[(size_t)(og * 125 + cell) * 1024 + (c >> 3) * 256 + (o & 31) * 8 + (c & 7)] =
            (short)f2bf(acc);
    }
}

// ---------------------------------------------------------------------------
// Conv: implicit GEMM via mfma_f32_32x32x16_bf16, BOTH operands from LDS.
// Grid 256 = [n2][d16][hb4][og2], 1 block/CU, 4 waves (1/SIMD).
// Wave tile: 32 o x 2 adjacent h-rows x 32 w; B-row carry (6 B-rows/plane).
// LDS: A dbuf 2x51200B + B dbuf 2x27648B = 157696 B.
// Per plane: stage A+B of plane l+1 at plane-l start (vmcnt-only FIFO,
// drained by the end-of-plane barrier after ~4000 cyc of compute cover);
// all operand loads are ds_read_b128 (lgkmcnt) -> fully decoupled.
// ---------------------------------------------------------------------------
#define ASLOT 25600          // shorts per A buffer (51200 B)
#define BBASE 51200          // short offset of B buffers
#define BSLOT 13824          // shorts per B buffer (27648 B)

__global__ __launch_bounds__(256, 1) void conv_mfma(const short* __restrict__ Kb,
                                                    const short* __restrict__ xp,
                                                    const float* __restrict__ bias,
                                                    float* __restrict__ out) {
    // XCD-aware chunked swizzle (256 % 8 == 0 -> bijective)
    const int sw = (blockIdx.x & 7) * 32 + (blockIdx.x >> 3);
    const int og = sw & 1;
    const int hb = (sw >> 1) & 3;
    const int d  = (sw >> 3) & 15;
    const int n  = sw >> 7;
    const int h0 = hb * 8;

    __shared__ short sL[2 * ASLOT + 2 * BSLOT];   // 157696 B

    const int tid  = threadIdx.x;
    const int wv   = tid >> 6;
    const int lane = tid & 63;
    const int wcol = lane & 31;
    const int hi   = lane >> 5;

    const short* srcA0 = Kb + (size_t)(og * 125) * 1024;     // + l*25*1024
    const short* srcB0 = xp + ((size_t)(n * 20 + d) * 36 + h0) * 1152;  // + l*41472

    // per-lane LDS read bases (shorts)
    const int aoff = wcol * 8 + hi * 256;                // + cell*1024 (+512 for ch1)
    const int boff = hi * 288 + wcol * 8;                // + row*1152 (+576 for ch1)

    f32x16 acc0, acc1;
    for (int e = 0; e < 16; ++e) { acc0[e] = 0.f; acc1[e] = 0.f; }

    bf16x8 Ab[3][2];      // [slot][ch] x5 i handled inside arrays below
    bf16x8 Aq[3][2][5];   // [slot][ch][i]
    bf16x8 Bq[3][2][5];   // [slot][ch][i]

#define STAGEA(L, BUF)                                                        \
    {                                                                         \
        const short* s_ = srcA0 + (size_t)(L) * 25600;                        \
        short* d_ = sL + (BUF) * ASLOT;                                       \
        _Pragma("unroll")                                                     \
        for (int k_ = 0; k_ < 12; ++k_) {                                     \
            const int t_ = k_ * 256 + tid;                                    \
            __builtin_amdgcn_global_load_lds(                                 \
                (const __attribute__((address_space(1))) unsigned int*)(s_ + t_ * 8), \
                (__attribute__((address_space(3))) unsigned int*)(d_ + t_ * 8), \
                16, 0, 0);                                                    \
        }                                                                     \
        if (tid < 128) {                                                      \
            const int t_ = 3072 + tid;                                        \
            __builtin_amdgcn_global_load_lds(                                 \
                (const __attribute__((address_space(1))) unsigned int*)(s_ + t_ * 8), \
                (__attribute__((address_space(3))) unsigned int*)(d_ + t_ * 8), \
                16, 0, 0);                                                    \
        }                                                                     \
    }

#define STAGEB(L, BUF)                                                        \
    {                                                                         \
        const short* s_ = srcB0 + (size_t)(L) * 41472;                        \
        short* d_ = sL + BBASE + (BUF) * BSLOT;                               \
        _Pragma("unroll")                                                     \
        for (int k_ = 0; k_ < 6; ++k_) {                                      \
            const int t_ = k_ * 256 + tid;                                    \
            __builtin_amdgcn_global_load_lds(                                 \
                (const __attribute__((address_space(1))) unsigned int*)(s_ + t_ * 8), \
                (__attribute__((address_space(3))) unsigned int*)(d_ + t_ * 8), \
                16, 0, 0);                                                    \
        }                                                                     \
        if (tid < 192) {                                                      \
            const int t_ = 1536 + tid;                                        \
            __builtin_amdgcn_global_load_lds(                                 \
                (const __attribute__((address_space(1))) unsigned int*)(s_ + t_ * 8), \
                (__attribute__((address_space(3))) unsigned int*)(d_ + t_ * 8), \
                16, 0, 0);                                                    \
        }                                                                     \
    }

#define LOADA(S, BUF, J)                                                      \
    {                                                                         \
        const short* pa_ = sL + (BUF) * ASLOT + (J) * 5120 + aoff;            \
        _Pragma("unroll")                                                     \
        for (int i_ = 0; i_ < 5; ++i_) {                                      \
            Aq[S][0][i_] = *reinterpret_cast<const bf16x8*>(pa_ + i_ * 1024); \
            Aq[S][1][i_] = *reinterpret_cast<const bf16x8*>(pa_ + i_ * 1024 + 512); \
        }                                                                     \
    }

#define LOADB(S, BUF, K)                                                      \
    {                                                                         \
        const short* pb_ = sL + BBASE + (BUF) * BSLOT + (2 * wv + (K)) * 1152 + boff; \
        _Pragma("unroll")                                                     \
        for (int i_ = 0; i_ < 5; ++i_) {                                      \
            Bq[S][0][i_] = *reinterpret_cast<const bf16x8*>(pb_ + i_ * 8);    \
            Bq[S][1][i_] = *reinterpret_cast<const bf16x8*>(pb_ + 576 + i_ * 8); \
        }                                                                     \
    }

#define MFMA_STEP(RA, S0, S1)                                                 \
    {                                                                         \
        __builtin_amdgcn_s_setprio(1);                                        \
        _Pragma("unroll")                                                     \
        for (int i_ = 0; i_ < 5; ++i_) {                                      \
            acc0 = __builtin_amdgcn_mfma_f32_32x32x16_bf16(Aq[RA][0][i_], Bq[S0][0][i_], acc0, 0, 0, 0); \
            acc1 = __builtin_amdgcn_mfma_f32_32x32x16_bf16(Aq[RA][0][i_], Bq[S1][0][i_], acc1, 0, 0, 0); \
            acc0 = __builtin_amdgcn_mfma_f32_32x32x16_bf16(Aq[RA][1][i_], Bq[S0][1][i_], acc0, 0, 0, 0); \
            acc1 = __builtin_amdgcn_mfma_f32_32x32x16_bf16(Aq[RA][1][i_], Bq[S1][1][i_], acc1, 0, 0, 0); \
        }                                                                     \
        __builtin_amdgcn_s_setprio(0);                                        \
    }

    // ---- prologue: stage plane 0 ----
    STAGEA(0, 0);
    STAGEB(0, 0);
    __syncthreads();

    #pragma unroll
    for (int l = 0; l < 5; ++l) {
        const int buf = l & 1;
        if (l < 4) { STAGEA(l + 1, buf ^ 1); STAGEB(l + 1, buf ^ 1); }
        LOADA(0, buf, 0); LOADA(1, buf, 1);
        LOADB(0, buf, 0); LOADB(1, buf, 1);
        #pragma unroll
        for (int j = 0; j < 5; ++j) {
            if (j < 3) LOADA((j + 2) % 3, buf, j + 2);
            if (j < 4) LOADB((j + 2) % 3, buf, j + 2);
            MFMA_STEP(j % 3, j % 3, (j + 1) % 3);
        }
        if (l < 4) __syncthreads();
    }

#undef STAGEA
#undef STAGEB
#undef LOADA
#undef LOADB
#undef MFMA_STEP

    // ---- epilogue: D layout col=lane&31 (w), row=(reg&3)+8*(reg>>2)+4*hi (o) ----
    const int h = h0 + 2 * wv;
    #pragma unroll
    for (int reg = 0; reg < 16; ++reg) {
        const int o = og * 32 + (reg & 3) + 8 * (reg >> 2) + 4 * hi;
        const float bo = bias[o];
        float* op = out + (((size_t)(n * 64 + o) * 16 + d) * 32 + h) * 32 + wcol;
        op[0]  = acc0[reg] + bo;
        op[32] = acc1[reg] + bo;
    }
}

extern "C" void kernel_launch(void* const* d_in, const int* in_sizes, int n_in,
                              void* d_out, int out_size, void* d_ws, size_t ws_size,
                              hipStream_t stream) {
    const float* x    = (const float*)d_in[0];
    const float* W    = (const float*)d_in[1];
    const float* P    = (const float*)d_in[2];
    const float* bias = (const float*)d_in[3];
    float* outp = (float*)d_out;

    short* Kb = (short*)d_ws;                          // 2*125*1024*2 = 512000 B
    short* xp = (short*)((char*)d_ws + 524288);        // 2*20*36*1152*2 = 3317760 B

    prep<<<1440 + 2048, 128, 0, stream>>>(x, W, P, xp, Kb);
    conv_mfma<<<256, 256, 0, stream>>>(Kb, xp, bias, outp);
}

// Round 7
// 27.018 us; speedup vs baseline: 1.7543x; 1.0602x over previous
//
#include <hip/hip_runtime.h>

#define OC 64
#define IC 32
#define KC 16

typedef __attribute__((ext_vector_type(8))) short bf16x8;
typedef __attribute__((ext_vector_type(16))) float f32x16;

__device__ inline unsigned short f2bf(float f) {
    unsigned u = __builtin_bit_cast(unsigned, f);
    unsigned r = (u + 0x7fffu + ((u >> 16) & 1u)) >> 16;
    return (unsigned short)r;
}

// ---------------------------------------------------------------------------
// Fused prep: blocks [0,1440): xpose; blocks [1440, 3488): build_k.
// xpose: x (NCDHW f32) -> bf16 xp[n][z=20][h=36][cg=4][w=36][c=8] (pad 2)
// build_k: trilinear kernel -> bf16 Kb[og=2][cell=125][kc=4][o=32][c8=8]
// ---------------------------------------------------------------------------
__global__ __launch_bounds__(128) void prep(const float* __restrict__ x,
                                            const float* __restrict__ W,
                                            const float* __restrict__ P,
                                            short* __restrict__ xp,
                                            short* __restrict__ Kb) {
    const int b = blockIdx.x;
    if (b < 1440) {
        // ---------------- xpose ----------------
        const int n = b / 720;
        const int rem = b - n * 720;
        const int z = rem / 36;
        const int h = rem - z * 36;
        const int zr = z - 2, hr = h - 2;
        short* orow = xp + (size_t)((n * 20 + z) * 36 + h) * 1152;

        if ((unsigned)zr >= 16u || (unsigned)hr >= 32u) {
            for (int idx = threadIdx.x; idx < 144; idx += 128)
                *reinterpret_cast<float4*>(orow + idx * 8) =
                    make_float4(0.f, 0.f, 0.f, 0.f);
            return;
        }

        __shared__ float sR[32][36];
        const float* xb = x + ((size_t)(n * 32) * 16 + zr) * 1024 + hr * 32;
        for (int idx = threadIdx.x; idx < 32 * 36; idx += 128) {
            const int c = idx / 36;
            const int w = idx - c * 36;
            const int wr = w - 2;
            float v = 0.f;
            if ((unsigned)wr < 32u) v = xb[(size_t)c * 16384 + wr];
            sR[c][w] = v;
        }
        __syncthreads();
        for (int idx = threadIdx.x; idx < 144; idx += 128) {
            const int cg = idx / 36;       // [cg][w] layout
            const int w  = idx - cg * 36;
            bf16x8 pk;
            #pragma unroll
            for (int e = 0; e < 8; ++e) pk[e] = (short)f2bf(sR[cg * 8 + e][w]);
            *reinterpret_cast<bf16x8*>(orow + idx * 8) = pk;
        }
    } else {
        // ---------------- build_k ----------------
        const int pair = b - 1440;        // 0..2047
        const int o = pair >> 5;
        const int c = pair & 31;
        const int cell = threadIdx.x;
        if (cell >= 125) return;
        const int l = cell / 25;
        const int j = (cell / 5) % 5;
        const int i = cell % 5;
        const float fl = (float)l, fj = (float)j, fi = (float)i;
        const int base = (o * IC + c) * KC;
        float acc = 0.f;
        #pragma unroll
        for (int k = 0; k < KC; ++k) {
            const float w  = W[base + k];
            const float p1 = P[0 * OC * IC * KC + base + k] + 2.0f;  // depth
            const float p2 = P[1 * OC * IC * KC + base + k] + 2.0f;  // width
            const float p3 = P[2 * OC * IC * KC + base + k] + 2.0f;  // height
            const float f1 = floorf(p1), r1 = p1 - f1;
            const float f2 = floorf(p2), r2 = p2 - f2;
            const float f3 = floorf(p3), r3 = p3 - f3;
            const float wl = (fl == f1) ? (1.f - r1) : ((fl == f1 + 1.f) ? r1 : 0.f);
            const float wj = (fj == f3) ? (1.f - r3) : ((fj == f3 + 1.f) ? r3 : 0.f);
            const float wi = (fi == f2) ? (1.f - r2) : ((fi == f2 + 1.f) ? r2 : 0.f);
            acc += w * (wl * wj * wi);
        }
        // Kb[og][cell][kc][o&31][c&7]
        const int og = o >> 5;
        Kb[(size_t)(og * 125 + cell) * 1024 + (c >> 3) * 256 + (o & 31) * 8 + (c & 7)] =
            (short)f2bf(acc);
    }
}

// ---------------------------------------------------------------------------
// Conv: implicit GEMM via mfma_f32_32x32x16_bf16, both operands from LDS.
// Grid 256 = [n2][d16][hb4][og2], 1 block/CU. Block 512 thr = 8 waves =
// 2/SIMD: wave (hp, g) = h-pair hp (2 rows) x c-half g (channels g*16..+15).
// Per-wave work halves (10 MFMA/step) -> per-CU pipe totals unchanged, but
// 2 waves/SIMD cover each other's lgkm/barrier stalls.
// LDS: A dbuf 2x51200B + B dbuf 2x27648B = 157696 B; c-half partials summed
// via a 32KB LDS exchange at the end.
// ---------------------------------------------------------------------------
#define ASLOT 25600          // shorts per A buffer (51200 B)
#define BBASE 51200          // short offset of B buffers
#define BSLOT 13824          // shorts per B buffer (27648 B)

__global__ __launch_bounds__(512, 1) void conv_mfma(const short* __restrict__ Kb,
                                                    const short* __restrict__ xp,
                                                    const float* __restrict__ bias,
                                                    float* __restrict__ out) {
    // XCD-aware chunked swizzle (256 % 8 == 0 -> bijective)
    const int sw = (blockIdx.x & 7) * 32 + (blockIdx.x >> 3);
    const int og = sw & 1;
    const int hb = (sw >> 1) & 3;
    const int d  = (sw >> 3) & 15;
    const int n  = sw >> 7;
    const int h0 = hb * 8;

    __shared__ short sL[2 * ASLOT + 2 * BSLOT];   // 157696 B

    const int tid  = threadIdx.x;
    const int wv   = tid >> 6;             // 0..7
    const int hp   = wv >> 1;              // h-pair 0..3
    const int g    = wv & 1;               // c-half
    const int lane = tid & 63;
    const int wcol = lane & 31;
    const int hi   = lane >> 5;

    const short* srcA0 = Kb + (size_t)(og * 125) * 1024;     // + l*25*1024
    const short* srcB0 = xp + ((size_t)(n * 20 + d) * 36 + h0) * 1152;  // + l*41472

    // per-lane LDS read bases (shorts)
    const int aoff = wcol * 8 + (g * 2 + hi) * 256;      // + buf*ASLOT + (cell)*1024
    const int boff = (g * 2 + hi) * 288 + wcol * 8;      // + BBASE + buf*BSLOT + row*1152

    f32x16 acc0, acc1;
    for (int e = 0; e < 16; ++e) { acc0[e] = 0.f; acc1[e] = 0.f; }

    bf16x8 Aq[3][5];   // [slot][i]
    bf16x8 Bq[3][5];   // [slot][i]

#define STAGEA(L, BUF)                                                        \
    {                                                                         \
        const short* s_ = srcA0 + (size_t)(L) * 25600;                        \
        short* d_ = sL + (BUF) * ASLOT;                                       \
        _Pragma("unroll")                                                     \
        for (int k_ = 0; k_ < 6; ++k_) {                                      \
            const int t_ = k_ * 512 + tid;                                    \
            __builtin_amdgcn_global_load_lds(                                 \
                (const __attribute__((address_space(1))) unsigned int*)(s_ + t_ * 8), \
                (__attribute__((address_space(3))) unsigned int*)(d_ + t_ * 8), \
                16, 0, 0);                                                    \
        }                                                                     \
        if (tid < 128) {                                                      \
            const int t_ = 3072 + tid;                                        \
            __builtin_amdgcn_global_load_lds(                                 \
                (const __attribute__((address_space(1))) unsigned int*)(s_ + t_ * 8), \
                (__attribute__((address_space(3))) unsigned int*)(d_ + t_ * 8), \
                16, 0, 0);                                                    \
        }                                                                     \
    }

#define STAGEB(L, BUF)                                                        \
    {                                                                         \
        const short* s_ = srcB0 + (size_t)(L) * 41472;                        \
        short* d_ = sL + BBASE + (BUF) * BSLOT;                               \
        _Pragma("unroll")                                                     \
        for (int k_ = 0; k_ < 3; ++k_) {                                      \
            const int t_ = k_ * 512 + tid;                                    \
            __builtin_amdgcn_global_load_lds(                                 \
                (const __attribute__((address_space(1))) unsigned int*)(s_ + t_ * 8), \
                (__attribute__((address_space(3))) unsigned int*)(d_ + t_ * 8), \
                16, 0, 0);                                                    \
        }                                                                     \
        if (tid < 192) {                                                      \
            const int t_ = 1536 + tid;                                        \
            __builtin_amdgcn_global_load_lds(                                 \
                (const __attribute__((address_space(1))) unsigned int*)(s_ + t_ * 8), \
                (__attribute__((address_space(3))) unsigned int*)(d_ + t_ * 8), \
                16, 0, 0);                                                    \
        }                                                                     \
    }

#define LOADA(S, BUF, J)                                                      \
    {                                                                         \
        const short* pa_ = sL + (BUF) * ASLOT + (J) * 5120 + aoff;            \
        _Pragma("unroll")                                                     \
        for (int i_ = 0; i_ < 5; ++i_)                                        \
            Aq[S][i_] = *reinterpret_cast<const bf16x8*>(pa_ + i_ * 1024);    \
    }

#define LOADB(S, BUF, K)                                                      \
    {                                                                         \
        const short* pb_ = sL + BBASE + (BUF) * BSLOT + (2 * hp + (K)) * 1152 + boff; \
        _Pragma("unroll")                                                     \
        for (int i_ = 0; i_ < 5; ++i_)                                        \
            Bq[S][i_] = *reinterpret_cast<const bf16x8*>(pb_ + i_ * 8);       \
    }

#define MFMA_STEP(RA, S0, S1)                                                 \
    {                                                                         \
        __builtin_amdgcn_s_setprio(1);                                        \
        _Pragma("unroll")                                                     \
        for (int i_ = 0; i_ < 5; ++i_) {                                      \
            acc0 = __builtin_amdgcn_mfma_f32_32x32x16_bf16(Aq[RA][i_], Bq[S0][i_], acc0, 0, 0, 0); \
            acc1 = __builtin_amdgcn_mfma_f32_32x32x16_bf16(Aq[RA][i_], Bq[S1][i_], acc1, 0, 0, 0); \
        }                                                                     \
        __builtin_amdgcn_s_setprio(0);                                        \
    }

    // ---- prologue: stage plane 0 ----
    STAGEA(0, 0);
    STAGEB(0, 0);
    __syncthreads();

    #pragma unroll
    for (int l = 0; l < 5; ++l) {
        const int buf = l & 1;
        if (l < 4) { STAGEA(l + 1, buf ^ 1); STAGEB(l + 1, buf ^ 1); }
        LOADA(0, buf, 0); LOADA(1, buf, 1);
        LOADB(0, buf, 0); LOADB(1, buf, 1);
        #pragma unroll
        for (int j = 0; j < 5; ++j) {
            if (j < 3) LOADA((j + 2) % 3, buf, j + 2);
            if (j < 4) LOADB((j + 2) % 3, buf, j + 2);
            MFMA_STEP(j % 3, j % 3, (j + 1) % 3);
        }
        if (l < 4) __syncthreads();
    }

#undef STAGEA
#undef STAGEB
#undef LOADA
#undef LOADB
#undef MFMA_STEP

    // ---- c-half reduction via LDS exchange + epilogue store ----
    // exchange layout: [hp][e 0..31][lane] f32  (conflict-free, 32 KB)
    __syncthreads();
    float* sF = reinterpret_cast<float*>(sL);
    if (g == 1) {
        #pragma unroll
        for (int e = 0; e < 16; ++e) {
            sF[hp * 2048 + e * 64 + lane]        = acc0[e];
            sF[hp * 2048 + (e + 16) * 64 + lane] = acc1[e];
        }
    }
    __syncthreads();
    if (g == 0) {
        const int h = h0 + 2 * hp;
        #pragma unroll
        for (int reg = 0; reg < 16; ++reg) {
            const int o = og * 32 + (reg & 3) + 8 * (reg >> 2) + 4 * hi;
            const float bo = bias[o];
            float* op = out + (((size_t)(n * 64 + o) * 16 + d) * 32 + h) * 32 + wcol;
            op[0]  = acc0[reg] + sF[hp * 2048 + reg * 64 + lane] + bo;
            op[32] = acc1[reg] + sF[hp * 2048 + (reg + 16) * 64 + lane] + bo;
        }
    }
}

extern "C" void kernel_launch(void* const* d_in, const int* in_sizes, int n_in,
                              void* d_out, int out_size, void* d_ws, size_t ws_size,
                              hipStream_t stream) {
    const float* x    = (const float*)d_in[0];
    const float* W    = (const float*)d_in[1];
    const float* P    = (const float*)d_in[2];
    const float* bias = (const float*)d_in[3];
    float* outp = (float*)d_out;

    short* Kb = (short*)d_ws;                          // 2*125*1024*2 = 512000 B
    short* xp = (short*)((char*)d_ws + 524288);        // 2*20*36*1152*2 = 3317760 B

    prep<<<1440 + 2048, 128, 0, stream>>>(x, W, P, xp, Kb);
    conv_mfma<<<256, 512, 0, stream>>>(Kb, xp, bias, outp);
}

// Round 8
// 26.145 us; speedup vs baseline: 1.8129x; 1.0334x over previous
//
#include <hip/hip_runtime.h>

#define OC 64
#define IC 32
#define KC 16

typedef __attribute__((ext_vector_type(8))) short bf16x8;
typedef __attribute__((ext_vector_type(16))) float f32x16;

__device__ inline unsigned short f2bf(float f) {
    unsigned u = __builtin_bit_cast(unsigned, f);
    unsigned r = (u + 0x7fffu + ((u >> 16) & 1u)) >> 16;
    return (unsigned short)r;
}

// ---------------------------------------------------------------------------
// Fused prep, 256-thr blocks, 2 work units each.
// blocks [0,720): xpose  -> bf16 xp[n][z=20][h=36][cg=4][w=36][c=8] (pad 2)
// blocks [720,1744): build_k -> bf16 Kb[og=2][cell=125][kc=4][o=32][c8=8]
// ---------------------------------------------------------------------------
__global__ __launch_bounds__(256) void prep(const float* __restrict__ x,
                                            const float* __restrict__ W,
                                            const float* __restrict__ P,
                                            short* __restrict__ xp,
                                            short* __restrict__ Kb) {
    __shared__ float sR[2][32][36];
    __shared__ float sWP[2][64];
    const int tid = threadIdx.x;
    const int u   = tid >> 7;
    const int ut  = tid & 127;
    const int b   = blockIdx.x;

    if (b < 720) {
        // ---------------- xpose (unit = one (n,z,h) row) ----------------
        const int ub = b * 2 + u;              // 0..1439
        const int n = ub / 720;
        const int rem = ub - n * 720;
        const int z = rem / 36;
        const int h = rem - z * 36;
        const int zr = z - 2, hr = h - 2;
        short* orow = xp + (size_t)((n * 20 + z) * 36 + h) * 1152;
        const bool edge = ((unsigned)zr >= 16u) || ((unsigned)hr >= 32u);

        if (!edge) {
            const float* xb = x + ((size_t)(n * 32) * 16 + zr) * 1024 + hr * 32;
            #pragma unroll
            for (int k = 0; k < 2; ++k) {      // 32c x 8 float4 along w
                const int id = ut + k * 128;
                const int c = id >> 3, w4 = id & 7;
                const float4 v = *reinterpret_cast<const float4*>(xb + c * 16384 + w4 * 4);
                float* dst = &sR[u][c][2 + w4 * 4];
                *reinterpret_cast<float2*>(dst)     = make_float2(v.x, v.y);
                *reinterpret_cast<float2*>(dst + 2) = make_float2(v.z, v.w);
            }
            {   // zero the w-pad columns 0,1,34,35
                const int c = ut >> 2, wz = ut & 3;
                const int w = (wz < 2) ? wz : 32 + wz;
                sR[u][c][w] = 0.f;
            }
        }
        __syncthreads();
        if (edge) {
            for (int idx = ut; idx < 144; idx += 128)
                *reinterpret_cast<float4*>(orow + idx * 8) =
                    make_float4(0.f, 0.f, 0.f, 0.f);
        } else {
            for (int idx = ut; idx < 144; idx += 128) {
                const int cg = idx / 36;
                const int w  = idx - cg * 36;
                bf16x8 pk;
                #pragma unroll
                for (int e = 0; e < 8; ++e) pk[e] = (short)f2bf(sR[u][cg * 8 + e][w]);
                *reinterpret_cast<bf16x8*>(orow + idx * 8) = pk;
            }
        }
    } else {
        // ---------------- build_k (unit = one (o,c) pair) ----------------
        const int pair = (b - 720) * 2 + u;    // 0..2047
        if (ut < 64)
            sWP[u][ut] = (ut < 16) ? W[pair * 16 + ut]
                                   : P[((ut >> 4) - 1) * 32768 + pair * 16 + (ut & 15)];
        __syncthreads();
        if (ut < 125) {
            const int cell = ut;
            const int l = cell / 25;
            const int j = (cell / 5) % 5;
            const int i = cell % 5;
            const float fl = (float)l, fj = (float)j, fi = (float)i;
            float acc = 0.f;
            #pragma unroll
            for (int k = 0; k < KC; ++k) {
                const float w  = sWP[u][k];
                const float p1 = sWP[u][16 + k] + 2.0f;  // depth
                const float p2 = sWP[u][32 + k] + 2.0f;  // width
                const float p3 = sWP[u][48 + k] + 2.0f;  // height
                const float f1 = floorf(p1), r1 = p1 - f1;
                const float f2 = floorf(p2), r2 = p2 - f2;
                const float f3 = floorf(p3), r3 = p3 - f3;
                const float wl = (fl == f1) ? (1.f - r1) : ((fl == f1 + 1.f) ? r1 : 0.f);
                const float wj = (fj == f3) ? (1.f - r3) : ((fj == f3 + 1.f) ? r3 : 0.f);
                const float wi = (fi == f2) ? (1.f - r2) : ((fi == f2 + 1.f) ? r2 : 0.f);
                acc += w * (wl * wj * wi);
            }
            const int o = pair >> 5, c = pair & 31;
            const int og = o >> 5;
            Kb[(size_t)(og * 125 + cell) * 1024 + (c >> 3) * 256 + (o & 31) * 8 + (c & 7)] =
                (short)f2bf(acc);
        }
    }
}

// ---------------------------------------------------------------------------
// Conv: implicit GEMM via mfma_f32_32x32x16_bf16, both operands LDS-staged.
// Grid 256 = [n2][d16][hb4][og2], 1 block/CU. Block 512 thr = 8 waves =
// (hp2 x g2 x s2): hp = 4 h-rows (4 accs), g = c-half, s = i-split
// ({0,1,2} vs {3,4}); s XOR-mapped so each SIMD hosts one s=0 + one s=1
// wave (60+40 MFMA/plane balanced). Cuts per-plane LDS reads 440->210 KB.
// LDS: A dbuf 2x51200 + B dbuf 2x27648 = 157696 B. launch_bounds(512,2)
// caps VGPR at 256 -> guaranteed 2 waves/SIMD.
// 4-partial (g,s) reduction via one LDS round-trip at the end.
// ---------------------------------------------------------------------------
#define ASLOT 25600          // shorts per A buffer (51200 B)
#define BBASE 51200          // short offset of B buffers
#define BSLOT 13824          // shorts per B buffer (27648 B)

__global__ __launch_bounds__(512, 2) void conv_mfma(const short* __restrict__ Kb,
                                                    const short* __restrict__ xp,
                                                    const float* __restrict__ bias,
                                                    float* __restrict__ out) {
    // XCD-aware chunked swizzle (256 % 8 == 0 -> bijective)
    const int sw = (blockIdx.x & 7) * 32 + (blockIdx.x >> 3);
    const int og = sw & 1;
    const int hb = (sw >> 1) & 3;
    const int d  = (sw >> 3) & 15;
    const int n  = sw >> 7;
    const int h0 = hb * 8;

    __shared__ short sL[2 * ASLOT + 2 * BSLOT];   // 157696 B

    const int tid  = threadIdx.x;
    const int wv   = tid >> 6;             // 0..7
    const int lane = tid & 63;
    const int wcol = lane & 31;
    const int hi   = lane >> 5;
    const int hp   = wv >> 2;              // h-quad (4 rows)
    const int g    = (wv >> 1) & 1;        // c-half
    const int s    = (wv ^ (wv >> 2)) & 1; // i-split, SIMD-balanced

    const short* srcA0 = Kb + (size_t)(og * 125) * 1024;
    const short* srcB0 = xp + ((size_t)(n * 20 + d) * 36 + h0) * 1152;

    const int aoff = wcol * 8 + (g * 2 + hi) * 256;
    const int boff = (g * 2 + hi) * 288 + wcol * 8;
    const int rb   = 4 * hp;               // wave's base B row

    f32x16 ac0, ac1, ac2, ac3;
    #pragma unroll
    for (int e = 0; e < 16; ++e) { ac0[e] = 0.f; ac1[e] = 0.f; ac2[e] = 0.f; ac3[e] = 0.f; }

    bf16x8 Aq[2][3];   // [parity][ii]
    bf16x8 Bq[5][3];   // [row slot][ii]

#define STAGEA(L, BUF)                                                        \
    {                                                                         \
        const short* s_ = srcA0 + (size_t)(L) * 25600;                        \
        short* d_ = sL + (BUF) * ASLOT;                                       \
        _Pragma("unroll")                                                     \
        for (int k_ = 0; k_ < 6; ++k_) {                                      \
            const int t_ = k_ * 512 + tid;                                    \
            __builtin_amdgcn_global_load_lds(                                 \
                (const __attribute__((address_space(1))) unsigned int*)(s_ + t_ * 8), \
                (__attribute__((address_space(3))) unsigned int*)(d_ + t_ * 8), \
                16, 0, 0);                                                    \
        }                                                                     \
        if (tid < 128) {                                                      \
            const int t_ = 3072 + tid;                                        \
            __builtin_amdgcn_global_load_lds(                                 \
                (const __attribute__((address_space(1))) unsigned int*)(s_ + t_ * 8), \
                (__attribute__((address_space(3))) unsigned int*)(d_ + t_ * 8), \
                16, 0, 0);                                                    \
        }                                                                     \
    }

#define STAGEB(L, BUF)                                                        \
    {                                                                         \
        const short* s_ = srcB0 + (size_t)(L) * 41472;                        \
        short* d_ = sL + BBASE + (BUF) * BSLOT;                               \
        _Pragma("unroll")                                                     \
        for (int k_ = 0; k_ < 3; ++k_) {                                      \
            const int t_ = k_ * 512 + tid;                                    \
            __builtin_amdgcn_global_load_lds(                                 \
                (const __attribute__((address_space(1))) unsigned int*)(s_ + t_ * 8), \
                (__attribute__((address_space(3))) unsigned int*)(d_ + t_ * 8), \
                16, 0, 0);                                                    \
        }                                                                     \
        if (tid < 192) {                                                      \
            const int t_ = 1536 + tid;                                        \
            __builtin_amdgcn_global_load_lds(                                 \
                (const __attribute__((address_space(1))) unsigned int*)(s_ + t_ * 8), \
                (__attribute__((address_space(3))) unsigned int*)(d_ + t_ * 8), \
                16, 0, 0);                                                    \
        }                                                                     \
    }

#define LOADA(PAR, BUF, J, I0, NI)                                            \
    {                                                                         \
        const short* pa_ = sL + (BUF) * ASLOT + ((J) * 5 + (I0)) * 1024 + aoff; \
        _Pragma("unroll")                                                     \
        for (int ii = 0; ii < (NI); ++ii)                                     \
            Aq[PAR][ii] = *reinterpret_cast<const bf16x8*>(pa_ + ii * 1024);  \
    }

#define LOADB(SLOT, BUF, RW, I0, NI)                                          \
    {                                                                         \
        const short* pb_ = sL + BBASE + (BUF) * BSLOT + (rb + (RW)) * 1152 + boff + (I0) * 8; \
        _Pragma("unroll")                                                     \
        for (int ii = 0; ii < (NI); ++ii)                                     \
            Bq[SLOT][ii] = *reinterpret_cast<const bf16x8*>(pb_ + ii * 8);    \
    }

#define MFMA_STEP(J, NI)                                                      \
    {                                                                         \
        __builtin_amdgcn_s_setprio(1);                                        \
        _Pragma("unroll")                                                     \
        for (int ii = 0; ii < (NI); ++ii) {                                   \
            const bf16x8 a_ = Aq[(J) & 1][ii];                                \
            ac0 = __builtin_amdgcn_mfma_f32_32x32x16_bf16(a_, Bq[(J) % 5][ii], ac0, 0, 0, 0);       \
            ac1 = __builtin_amdgcn_mfma_f32_32x32x16_bf16(a_, Bq[((J) + 1) % 5][ii], ac1, 0, 0, 0); \
            ac2 = __builtin_amdgcn_mfma_f32_32x32x16_bf16(a_, Bq[((J) + 2) % 5][ii], ac2, 0, 0, 0); \
            ac3 = __builtin_amdgcn_mfma_f32_32x32x16_bf16(a_, Bq[((J) + 3) % 5][ii], ac3, 0, 0, 0); \
        }                                                                     \
        __builtin_amdgcn_s_setprio(0);                                        \
    }

#define MAIN(I0, NI)                                                          \
    {                                                                         \
        STAGEA(0, 0); STAGEB(0, 0);                                           \
        __syncthreads();                                                      \
        _Pragma("unroll")                                                     \
        for (int l = 0; l < 5; ++l) {                                         \
            const int buf = l & 1;                                            \
            if (l < 4) { STAGEA(l + 1, buf ^ 1); STAGEB(l + 1, buf ^ 1); }    \
            LOADA(0, buf, 0, I0, NI);                                         \
            LOADB(0, buf, 0, I0, NI);                                         \
            LOADB(1, buf, 1, I0, NI);                                         \
            LOADB(2, buf, 2, I0, NI);                                         \
            LOADB(3, buf, 3, I0, NI);                                         \
            _Pragma("unroll")                                                 \
            for (int j = 0; j < 5; ++j) {                                     \
                if (j < 4) {                                                  \
                    LOADA((j + 1) & 1, buf, j + 1, I0, NI);                   \
                    LOADB((j + 4) % 5, buf, j + 4, I0, NI);                   \
                }                                                             \
                MFMA_STEP(j, NI);                                             \
            }                                                                 \
            if (l < 4) __syncthreads();                                       \
        }                                                                     \
    }

    if (s == 0) { MAIN(0, 3) } else { MAIN(3, 2) }

#undef STAGEA
#undef STAGEB
#undef LOADA
#undef LOADB
#undef MFMA_STEP
#undef MAIN

    // ---- (g,s) 4-partial reduction via LDS, then store ----
    // layout: sF[gs=4][hp=2][r=4][e=16][lane=64] f32 = 131072 B
    __syncthreads();
    float* sF = reinterpret_cast<float*>(sL);
    const int wbase = (g * 2 + s) * 2 + hp;
#define WR(R, A)                                                              \
    { _Pragma("unroll")                                                       \
      for (int e = 0; e < 16; ++e)                                            \
          sF[((wbase * 4 + (R)) * 16 + e) * 64 + lane] = A[e]; }
    WR(0, ac0) WR(1, ac1) WR(2, ac2) WR(3, ac3)
#undef WR
    __syncthreads();

    // wave wv stores output row h0+wv (hp'=wv>>2, r'=wv&3)
    const int hpR = wv >> 2, rR = wv & 3;
    const int h = h0 + wv;
    #pragma unroll
    for (int e = 0; e < 16; ++e) {
        float v = 0.f;
        #pragma unroll
        for (int q = 0; q < 4; ++q)
            v += sF[(((q * 2 + hpR) * 4 + rR) * 16 + e) * 64 + lane];
        const int o = og * 32 + (e & 3) + 8 * (e >> 2) + 4 * hi;
        out[((size_t)(n * 64 + o) * 16 + d) * 1024 + h * 32 + wcol] = v + bias[o];
    }
}

extern "C" void kernel_launch(void* const* d_in, const int* in_sizes, int n_in,
                              void* d_out, int out_size, void* d_ws, size_t ws_size,
                              hipStream_t stream) {
    const float* x    = (const float*)d_in[0];
    const float* W    = (const float*)d_in[1];
    const float* P    = (const float*)d_in[2];
    const float* bias = (const float*)d_in[3];
    float* outp = (float*)d_out;

    short* Kb = (short*)d_ws;                          // 2*125*1024*2 = 512000 B
    short* xp = (short*)((char*)d_ws + 524288);        // 2*20*36*1152*2 = 3317760 B

    prep<<<1744, 256, 0, stream>>>(x, W, P, xp, Kb);
    conv_mfma<<<256, 512, 0, stream>>>(Kb, xp, bias, outp);
}

// Round 9
// 25.595 us; speedup vs baseline: 1.8518x; 1.0215x over previous
//
#include <hip/hip_runtime.h>

#define OC 64
#define IC 32
#define KC 16

typedef __attribute__((ext_vector_type(8))) short bf16x8;
typedef __attribute__((ext_vector_type(16))) float f32x16;

__device__ inline unsigned short f2bf(float f) {
    unsigned u = __builtin_bit_cast(unsigned, f);
    unsigned r = (u + 0x7fffu + ((u >> 16) & 1u)) >> 16;
    return (unsigned short)r;
}

// ---------------------------------------------------------------------------
// Fused prep, 256-thr blocks, 2 work units each.
// blocks [0,720): xpose  -> bf16 xp[n][z=20][h=36][cg=4][w=36][c=8] (pad 2)
// blocks [720,1744): build_k -> bf16 Kb[og=2][cell=125][kc=4][o=32][c8=8]
// ---------------------------------------------------------------------------
__global__ __launch_bounds__(256) void prep(const float* __restrict__ x,
                                            const float* __restrict__ W,
                                            const float* __restrict__ P,
                                            short* __restrict__ xp,
                                            short* __restrict__ Kb) {
    __shared__ float sR[2][32][36];
    __shared__ float sWP[2][64];
    const int tid = threadIdx.x;
    const int u   = tid >> 7;
    const int ut  = tid & 127;
    const int b   = blockIdx.x;

    if (b < 720) {
        // ---------------- xpose (unit = one (n,z,h) row) ----------------
        const int ub = b * 2 + u;              // 0..1439
        const int n = ub / 720;
        const int rem = ub - n * 720;
        const int z = rem / 36;
        const int h = rem - z * 36;
        const int zr = z - 2, hr = h - 2;
        short* orow = xp + (size_t)((n * 20 + z) * 36 + h) * 1152;
        const bool edge = ((unsigned)zr >= 16u) || ((unsigned)hr >= 32u);

        if (!edge) {
            const float* xb = x + ((size_t)(n * 32) * 16 + zr) * 1024 + hr * 32;
            #pragma unroll
            for (int k = 0; k < 2; ++k) {      // 32c x 8 float4 along w
                const int id = ut + k * 128;
                const int c = id >> 3, w4 = id & 7;
                const float4 v = *reinterpret_cast<const float4*>(xb + c * 16384 + w4 * 4);
                float* dst = &sR[u][c][2 + w4 * 4];
                *reinterpret_cast<float2*>(dst)     = make_float2(v.x, v.y);
                *reinterpret_cast<float2*>(dst + 2) = make_float2(v.z, v.w);
            }
            {   // zero the w-pad columns 0,1,34,35
                const int c = ut >> 2, wz = ut & 3;
                const int w = (wz < 2) ? wz : 32 + wz;
                sR[u][c][w] = 0.f;
            }
        }
        __syncthreads();
        if (edge) {
            for (int idx = ut; idx < 144; idx += 128)
                *reinterpret_cast<float4*>(orow + idx * 8) =
                    make_float4(0.f, 0.f, 0.f, 0.f);
        } else {
            for (int idx = ut; idx < 144; idx += 128) {
                const int cg = idx / 36;
                const int w  = idx - cg * 36;
                bf16x8 pk;
                #pragma unroll
                for (int e = 0; e < 8; ++e) pk[e] = (short)f2bf(sR[u][cg * 8 + e][w]);
                *reinterpret_cast<bf16x8*>(orow + idx * 8) = pk;
            }
        }
    } else {
        // ---------------- build_k (unit = one (o,c) pair) ----------------
        const int pair = (b - 720) * 2 + u;    // 0..2047
        if (ut < 64)
            sWP[u][ut] = (ut < 16) ? W[pair * 16 + ut]
                                   : P[((ut >> 4) - 1) * 32768 + pair * 16 + (ut & 15)];
        __syncthreads();
        if (ut < 125) {
            const int cell = ut;
            const int l = cell / 25;
            const int j = (cell / 5) % 5;
            const int i = cell % 5;
            const float fl = (float)l, fj = (float)j, fi = (float)i;
            float acc = 0.f;
            #pragma unroll
            for (int k = 0; k < KC; ++k) {
                const float w  = sWP[u][k];
                const float p1 = sWP[u][16 + k] + 2.0f;  // depth
                const float p2 = sWP[u][32 + k] + 2.0f;  // width
                const float p3 = sWP[u][48 + k] + 2.0f;  // height
                const float f1 = floorf(p1), r1 = p1 - f1;
                const float f2 = floorf(p2), r2 = p2 - f2;
                const float f3 = floorf(p3), r3 = p3 - f3;
                const float wl = (fl == f1) ? (1.f - r1) : ((fl == f1 + 1.f) ? r1 : 0.f);
                const float wj = (fj == f3) ? (1.f - r3) : ((fj == f3 + 1.f) ? r3 : 0.f);
                const float wi = (fi == f2) ? (1.f - r2) : ((fi == f2 + 1.f) ? r2 : 0.f);
                acc += w * (wl * wj * wi);
            }
            const int o = pair >> 5, c = pair & 31;
            const int og = o >> 5;
            Kb[(size_t)(og * 125 + cell) * 1024 + (c >> 3) * 256 + (o & 31) * 8 + (c & 7)] =
                (short)f2bf(acc);
        }
    }
}

// ---------------------------------------------------------------------------
// Conv: implicit GEMM via mfma_f32_32x32x16_bf16, both operands LDS-staged.
// Grid 256 = [n2][d16][hb4][og2], 1 block/CU. Block 512 thr = 8 waves =
// (hp2 x g2 x s2). launch_bounds(512,2) -> 2 waves/SIMD guaranteed.
// Changes vs r8: STAGEB deferred to after step j=0 (spread VMEM issue);
// epilogue partial-exchange vectorized to b128 ([cls][hp][r][eg][lane][4f32]).
// ---------------------------------------------------------------------------
#define ASLOT 25600          // shorts per A buffer (51200 B)
#define BBASE 51200          // short offset of B buffers
#define BSLOT 13824          // shorts per B buffer (27648 B)

__global__ __launch_bounds__(512, 2) void conv_mfma(const short* __restrict__ Kb,
                                                    const short* __restrict__ xp,
                                                    const float* __restrict__ bias,
                                                    float* __restrict__ out) {
    // XCD-aware chunked swizzle (256 % 8 == 0 -> bijective)
    const int sw = (blockIdx.x & 7) * 32 + (blockIdx.x >> 3);
    const int og = sw & 1;
    const int hb = (sw >> 1) & 3;
    const int d  = (sw >> 3) & 15;
    const int n  = sw >> 7;
    const int h0 = hb * 8;

    __shared__ short sL[2 * ASLOT + 2 * BSLOT];   // 157696 B

    const int tid  = threadIdx.x;
    const int wv   = tid >> 6;             // 0..7
    const int lane = tid & 63;
    const int wcol = lane & 31;
    const int hi   = lane >> 5;
    const int hp   = wv >> 2;              // h-quad (4 rows)
    const int g    = (wv >> 1) & 1;        // c-half
    const int s    = (wv ^ (wv >> 2)) & 1; // i-split, SIMD-balanced

    const short* srcA0 = Kb + (size_t)(og * 125) * 1024;
    const short* srcB0 = xp + ((size_t)(n * 20 + d) * 36 + h0) * 1152;

    const int aoff = wcol * 8 + (g * 2 + hi) * 256;
    const int boff = (g * 2 + hi) * 288 + wcol * 8;
    const int rb   = 4 * hp;               // wave's base B row

    f32x16 ac0, ac1, ac2, ac3;
    #pragma unroll
    for (int e = 0; e < 16; ++e) { ac0[e] = 0.f; ac1[e] = 0.f; ac2[e] = 0.f; ac3[e] = 0.f; }

    bf16x8 Aq[2][3];   // [parity][ii]
    bf16x8 Bq[5][3];   // [row slot][ii]

#define STAGEA(L, BUF)                                                        \
    {                                                                         \
        const short* s_ = srcA0 + (size_t)(L) * 25600;                        \
        short* d_ = sL + (BUF) * ASLOT;                                       \
        _Pragma("unroll")                                                     \
        for (int k_ = 0; k_ < 6; ++k_) {                                      \
            const int t_ = k_ * 512 + tid;                                    \
            __builtin_amdgcn_global_load_lds(                                 \
                (const __attribute__((address_space(1))) unsigned int*)(s_ + t_ * 8), \
                (__attribute__((address_space(3))) unsigned int*)(d_ + t_ * 8), \
                16, 0, 0);                                                    \
        }                                                                     \
        if (tid < 128) {                                                      \
            const int t_ = 3072 + tid;                                        \
            __builtin_amdgcn_global_load_lds(                                 \
                (const __attribute__((address_space(1))) unsigned int*)(s_ + t_ * 8), \
                (__attribute__((address_space(3))) unsigned int*)(d_ + t_ * 8), \
                16, 0, 0);                                                    \
        }                                                                     \
    }

#define STAGEB(L, BUF)                                                        \
    {                                                                         \
        const short* s_ = srcB0 + (size_t)(L) * 41472;                        \
        short* d_ = sL + BBASE + (BUF) * BSLOT;                               \
        _Pragma("unroll")                                                     \
        for (int k_ = 0; k_ < 3; ++k_) {                                      \
            const int t_ = k_ * 512 + tid;                                    \
            __builtin_amdgcn_global_load_lds(                                 \
                (const __attribute__((address_space(1))) unsigned int*)(s_ + t_ * 8), \
                (__attribute__((address_space(3))) unsigned int*)(d_ + t_ * 8), \
                16, 0, 0);                                                    \
        }                                                                     \
        if (tid < 192) {                                                      \
            const int t_ = 1536 + tid;                                        \
            __builtin_amdgcn_global_load_lds(                                 \
                (const __attribute__((address_space(1))) unsigned int*)(s_ + t_ * 8), \
                (__attribute__((address_space(3))) unsigned int*)(d_ + t_ * 8), \
                16, 0, 0);                                                    \
        }                                                                     \
    }

#define LOADA(PAR, BUF, J, I0, NI)                                            \
    {                                                                         \
        const short* pa_ = sL + (BUF) * ASLOT + ((J) * 5 + (I0)) * 1024 + aoff; \
        _Pragma("unroll")                                                     \
        for (int ii = 0; ii < (NI); ++ii)                                     \
            Aq[PAR][ii] = *reinterpret_cast<const bf16x8*>(pa_ + ii * 1024);  \
    }

#define LOADB(SLOT, BUF, RW, I0, NI)                                          \
    {                                                                         \
        const short* pb_ = sL + BBASE + (BUF) * BSLOT + (rb + (RW)) * 1152 + boff + (I0) * 8; \
        _Pragma("unroll")                                                     \
        for (int ii = 0; ii < (NI); ++ii)                                     \
            Bq[SLOT][ii] = *reinterpret_cast<const bf16x8*>(pb_ + ii * 8);    \
    }

#define MFMA_STEP(J, NI)                                                      \
    {                                                                         \
        __builtin_amdgcn_s_setprio(1);                                        \
        _Pragma("unroll")                                                     \
        for (int ii = 0; ii < (NI); ++ii) {                                   \
            const bf16x8 a_ = Aq[(J) & 1][ii];                                \
            ac0 = __builtin_amdgcn_mfma_f32_32x32x16_bf16(a_, Bq[(J) % 5][ii], ac0, 0, 0, 0);       \
            ac1 = __builtin_amdgcn_mfma_f32_32x32x16_bf16(a_, Bq[((J) + 1) % 5][ii], ac1, 0, 0, 0); \
            ac2 = __builtin_amdgcn_mfma_f32_32x32x16_bf16(a_, Bq[((J) + 2) % 5][ii], ac2, 0, 0, 0); \
            ac3 = __builtin_amdgcn_mfma_f32_32x32x16_bf16(a_, Bq[((J) + 3) % 5][ii], ac3, 0, 0, 0); \
        }                                                                     \
        __builtin_amdgcn_s_setprio(0);                                        \
    }

#define MAIN(I0, NI)                                                          \
    {                                                                         \
        STAGEA(0, 0); STAGEB(0, 0);                                           \
        __syncthreads();                                                      \
        _Pragma("unroll")                                                     \
        for (int l = 0; l < 5; ++l) {                                         \
            const int buf = l & 1;                                            \
            if (l < 4) STAGEA(l + 1, buf ^ 1);                                \
            LOADA(0, buf, 0, I0, NI);                                         \
            LOADB(0, buf, 0, I0, NI);                                         \
            LOADB(1, buf, 1, I0, NI);                                         \
            LOADB(2, buf, 2, I0, NI);                                         \
            LOADB(3, buf, 3, I0, NI);                                         \
            _Pragma("unroll")                                                 \
            for (int j = 0; j < 5; ++j) {                                     \
                if (j < 4) {                                                  \
                    LOADA((j + 1) & 1, buf, j + 1, I0, NI);                   \
                    LOADB((j + 4) % 5, buf, j + 4, I0, NI);                   \
                }                                                             \
                MFMA_STEP(j, NI);                                             \
                if (j == 0 && l < 4) STAGEB(l + 1, buf ^ 1);                  \
            }                                                                 \
            if (l < 4) __syncthreads();                                       \
        }                                                                     \
    }

    if (s == 0) { MAIN(0, 3) } else { MAIN(3, 2) }

#undef STAGEA
#undef STAGEB
#undef LOADA
#undef LOADB
#undef MFMA_STEP
#undef MAIN

    // ---- (g,s) 4-partial reduction via vectorized LDS exchange ----
    // layout: sF[cls4][hp2][r4][eg4][lane64][4 f32] = 131072 B, all b128 ops
    __syncthreads();
    float* sF = reinterpret_cast<float*>(sL);
    const int cls = g * 2 + s;
#define PWRITE(R, A)                                                          \
    {                                                                         \
        float* p_ = sF + ((((cls * 2 + hp) * 4 + (R)) * 4) * 64 + lane) * 4;  \
        _Pragma("unroll")                                                     \
        for (int eg = 0; eg < 4; ++eg) {                                      \
            float4 v_ = make_float4(A[4 * eg], A[4 * eg + 1],                 \
                                    A[4 * eg + 2], A[4 * eg + 3]);            \
            *reinterpret_cast<float4*>(p_ + eg * 256) = v_;                   \
        }                                                                     \
    }
    PWRITE(0, ac0) PWRITE(1, ac1) PWRITE(2, ac2) PWRITE(3, ac3)
#undef PWRITE
    __syncthreads();

    // wave wv stores output row h0+wv (hpR=wv>>2, rR=wv&3)
    const int hpR = wv >> 2, rR = wv & 3;
    const int h = h0 + wv;
    #pragma unroll
    for (int eg = 0; eg < 4; ++eg) {
        float4 sv = make_float4(0.f, 0.f, 0.f, 0.f);
        #pragma unroll
        for (int c4 = 0; c4 < 4; ++c4) {
            const float4 t = *reinterpret_cast<const float4*>(
                sF + ((((c4 * 2 + hpR) * 4 + rR) * 4 + eg) * 64 + lane) * 4);
            sv.x += t.x; sv.y += t.y; sv.z += t.z; sv.w += t.w;
        }
        #pragma unroll
        for (int k = 0; k < 4; ++k) {
            const int e = eg * 4 + k;
            const int o = og * 32 + (e & 3) + 8 * (e >> 2) + 4 * hi;
            const float v = (k == 0) ? sv.x : (k == 1) ? sv.y : (k == 2) ? sv.z : sv.w;
            out[((size_t)(n * 64 + o) * 16 + d) * 1024 + h * 32 + wcol] = v + bias[o];
        }
    }
}

extern "C" void kernel_launch(void* const* d_in, const int* in_sizes, int n_in,
                              void* d_out, int out_size, void* d_ws, size_t ws_size,
                              hipStream_t stream) {
    const float* x    = (const float*)d_in[0];
    const float* W    = (const float*)d_in[1];
    const float* P    = (const float*)d_in[2];
    const float* bias = (const float*)d_in[3];
    float* outp = (float*)d_out;

    short* Kb = (short*)d_ws;                          // 2*125*1024*2 = 512000 B
    short* xp = (short*)((char*)d_ws + 524288);        // 2*20*36*1152*2 = 3317760 B

    prep<<<1744, 256, 0, stream>>>(x, W, P, xp, Kb);
    conv_mfma<<<256, 512, 0, stream>>>(Kb, xp, bias, outp);
}